// Round 7
// baseline (607.743 us; speedup 1.0000x reference)
//
#include <hip/hip_runtime.h>
#include <hip/hip_bf16.h>
#include <hip/hip_fp16.h>
#include <stdint.h>
#include <stddef.h>

#define NN   100000   // nodes
#define NE   1600000  // edges
#define INC  512      // in channels
#define HID  256      // hidden
#define OC   40       // out channels
#define OCP  48       // padded out channels (3 x 16 col-tiles)

#define LDS1 144      // int8 tile row stride in bytes (128 + 16): conflict-free
#define LDSB2 272     // lB2 row stride bytes (256 + 16)

#define NBKT ((NN + 255) / 256)   // 391 coarse buckets of 256 nodes
#define NMT1 ((NN + 127) / 128)   // 782 gemm1 row tiles
#define GEMM1_BLKS (((NMT1 + 7) / 8) * 16)   // 1568

// L1 merged launch: absmax segments + chist
#define ABS_X_BLKS  2048
#define ABS_W1_BLKS 128
#define ABS_W2_BLKS 16
#define ABS_TOT     (ABS_X_BLKS + ABS_W1_BLKS + ABS_W2_BLKS)   // 2192
#define CHIST_BLKS  256
// L3 merged launch: quantw1 + quantw2 + bin (quantx fused into gemm1)
#define QW1_BLKS    128
#define QW2_BLKS    16
#define QW_TOT      (QW1_BLKS + QW2_BLKS)   // 144
#define BIN_BLOCKS  400
#define BIN_EPB     (NE / BIN_BLOCKS)   // 4000

typedef float  f32x4  __attribute__((ext_vector_type(4)));
typedef int    i32x4  __attribute__((ext_vector_type(4)));
typedef _Float16 f16x8 __attribute__((ext_vector_type(8)));

// ---- device-global scratch ----
__device__ unsigned g_amax_bits[4];          // 0:x 1:w1 2:w2 3:h
__device__ float    g_dinv[NN];
__device__ signed char g_qw1[HID * INC];         // int8
__device__ signed char g_qw2[OCP * HID];         // int8, rows 40..47 zero
__device__ _Float16 g_h[(size_t)NN * HID];   // relu(fc1) fp16
__device__ float    g_z[(size_t)NN * OC];    // fc2 output
// CSR-by-destination (two-level binned build)
__device__ unsigned g_chist[NBKT];
__device__ unsigned g_cstart[NBKT + 1];
__device__ unsigned g_ccur[NBKT];
__device__ uint2    g_bin[NE];
__device__ unsigned g_rowstart[NN + 1];
__device__ int      g_csr_src[NE];

__device__ __forceinline__ float quantf(float v, float rs) {
    return fminf(fmaxf(rintf(v * rs), -128.0f), 127.0f);
}
__device__ __forceinline__ int pack4(float a, float b, float c, float d, float rs) {
    int q0 = (int)quantf(a, rs), q1 = (int)quantf(b, rs);
    int q2 = (int)quantf(c, rs), q3 = (int)quantf(d, rs);
    return (q0 & 255) | ((q1 & 255) << 8) | ((q2 & 255) << 16) | ((q3 & 255) << 24);
}
__device__ __forceinline__ i32x4 pack16(f32x4 v0, f32x4 v1, f32x4 v2, f32x4 v3, float rs) {
    i32x4 o;
    o[0] = pack4(v0.x, v0.y, v0.z, v0.w, rs);
    o[1] = pack4(v1.x, v1.y, v1.z, v1.w, rs);
    o[2] = pack4(v2.x, v2.y, v2.z, v2.w, rs);
    o[3] = pack4(v3.x, v3.y, v3.z, v3.w, rs);
    return o;
}

// ---------------- init (tiny; must precede L1) ----------------
__global__ void init_kernel() {
    int idx = blockIdx.x * blockDim.x + threadIdx.x;
    int stride = gridDim.x * blockDim.x;
    for (int i = idx; i < NBKT; i += stride) g_chist[i] = 0u;
    for (int i = idx; i < (OCP * HID) / 4; i += stride) ((int*)g_qw2)[i] = 0;
    if (idx < 4) g_amax_bits[idx] = 0u;
}

// ---------------- L1: absmax(x|w1|w2) blocks [0,2192) + chist blocks [2192,2448) ----------------
__global__ void __launch_bounds__(256) absmax_chist_kernel(const float* __restrict__ x,
                                                           const float* __restrict__ w1,
                                                           const float* __restrict__ w2,
                                                           const int* __restrict__ ei) {
    __shared__ unsigned shist[NBKT];
    __shared__ float sm[4];
    int b = blockIdx.x;
    int t = threadIdx.x;
    if (b < ABS_TOT) {
        const float* src; int n4, slot, bbase, nb;
        if (b < ABS_X_BLKS) {
            src = x;  n4 = (NN * INC) / 4;  slot = 0; bbase = 0;                       nb = ABS_X_BLKS;
        } else if (b < ABS_X_BLKS + ABS_W1_BLKS) {
            src = w1; n4 = (HID * INC) / 4; slot = 1; bbase = ABS_X_BLKS;              nb = ABS_W1_BLKS;
        } else {
            src = w2; n4 = (OC * HID) / 4;  slot = 2; bbase = ABS_X_BLKS + ABS_W1_BLKS; nb = ABS_W2_BLKS;
        }
        int idx = (b - bbase) * 256 + t;
        int stride = nb * 256;
        const f32x4* s4 = (const f32x4*)src;
        float m = 0.0f;
        for (int i = idx; i < n4; i += stride) {
            f32x4 v = s4[i];
            m = fmaxf(m, fmaxf(fmaxf(fabsf(v.x), fabsf(v.y)),
                               fmaxf(fabsf(v.z), fabsf(v.w))));
        }
#pragma unroll
        for (int off = 32; off > 0; off >>= 1) m = fmaxf(m, __shfl_xor(m, off, 64));
        if ((t & 63) == 0) sm[t >> 6] = m;
        __syncthreads();
        if (t == 0) {
            float mm = fmaxf(fmaxf(sm[0], sm[1]), fmaxf(sm[2], sm[3]));
            atomicMax(&g_amax_bits[slot], __float_as_uint(mm));
        }
    } else {
        // chist: per-block LDS histogram of dst>>8, flush with global atomics
        const int* dst = ei + NE;
        for (int i = t; i < NBKT; i += 256) shist[i] = 0u;
        __syncthreads();
        int idx = (b - ABS_TOT) * 256 + t;
        int stride = CHIST_BLKS * 256;
        for (int e = idx; e < NE; e += stride) atomicAdd(&shist[dst[e] >> 8], 1u);
        __syncthreads();
        for (int i = t; i < NBKT; i += 256) {
            unsigned c = shist[i];
            if (c) atomicAdd(&g_chist[i], c);
        }
    }
}

// ---------------- coarse scan ----------------
__global__ void cscan_kernel() {
    int t = threadIdx.x;
    unsigned v = (t < NBKT) ? g_chist[t] : 0u;
    int lane = t & 63, wv = t >> 6;
    unsigned sc = v;
#pragma unroll
    for (int off = 1; off < 64; off <<= 1) {
        unsigned n = __shfl_up(sc, off, 64);
        if (lane >= off) sc += n;
    }
    __shared__ unsigned ws[8];
    if (lane == 63) ws[wv] = sc;
    __syncthreads();
    unsigned woff = 0;
    for (int w = 0; w < 8; w++) if (w < wv) woff += ws[w];
    unsigned excl = woff + sc - v;
    if (t < NBKT) { g_cstart[t] = excl; g_ccur[t] = excl; }
    if (t == 0) g_cstart[NBKT] = NE;
}

// ---------------- L3: quantw1 [0,128) + quantw2 [128,144) + bin [144,544) ----------------
__global__ void __launch_bounds__(256) quant_bin_kernel(const float* __restrict__ w1,
                                                        const float* __restrict__ w2,
                                                        const int* __restrict__ ei) {
    __shared__ unsigned hist[NBKT];
    __shared__ unsigned base[NBKT];
    int b = blockIdx.x;
    int t = threadIdx.x;
    if (b < QW_TOT) {
        const float* src; int* dst; int nint, slot, bbase, nb;
        if (b < QW1_BLKS) { src = w1; dst = (int*)g_qw1; nint = (HID * INC) / 4; slot = 1; bbase = 0;        nb = QW1_BLKS; }
        else              { src = w2; dst = (int*)g_qw2; nint = (OC * HID) / 4;  slot = 2; bbase = QW1_BLKS; nb = QW2_BLKS; }
        float rs = 1.0f / (__uint_as_float(g_amax_bits[slot]) / 127.0f + 1e-12f);
        int idx = (b - bbase) * 256 + t;
        int stride = nb * 256;
        for (int i = idx; i < nint; i += stride) {
            f32x4 v = *(const f32x4*)(src + (size_t)i * 4);
            dst[i] = pack4(v.x, v.y, v.z, v.w, rs);
        }
    } else {
        // bin: group edges by coarse bucket
        const int* srcp = ei;
        const int* dstp = ei + NE;
        int bb = b - QW_TOT;
        int e0 = bb * BIN_EPB, e1 = e0 + BIN_EPB;
        for (int i = t; i < NBKT; i += 256) hist[i] = 0u;
        __syncthreads();
        for (int e = e0 + t; e < e1; e += 256) atomicAdd(&hist[dstp[e] >> 8], 1u);
        __syncthreads();
        for (int i = t; i < NBKT; i += 256) {
            unsigned c = hist[i];
            base[i] = c ? atomicAdd(&g_ccur[i], c) : 0u;
            hist[i] = 0u;   // reuse as local cursor
        }
        __syncthreads();
        for (int e = e0 + t; e < e1; e += 256) {
            int d = dstp[e], s = srcp[e];
            int bk = d >> 8;
            unsigned r = atomicAdd(&hist[bk], 1u);
            g_bin[base[bk] + r] = make_uint2((unsigned)s, (unsigned)d);
        }
    }
}

// ---------------- L4 (512 threads): gemm1 [0,1568) + local [1568,1959) ----------------
// gemm1: h = relu(s * (fq(x) @ qw1^T) + b1) -> fp16, amax(h).  Restructured for
// occupancy + latency hiding:
//   * single-buffered LDS (36.9 KB -> 4 blocks/CU by LDS; was 73.7 KB / 2)
//   * 8 waves x (32x64) output each; acc = 32 VGPR/thread
//   * T14 split staging: raw A(fp32)/B(int8) loads for kit k+1 issue AFTER the
//     post-write barrier and BEFORE the ds_read+MFMA phase, so the vmcnt drain
//     at the end-of-kit barrier lands after ~1000 cyc of covering work.  Pack
//     (bit-identical quantx math) runs from registers at the next kit top.
__global__ void __launch_bounds__(512) gemm1_local_kernel(const float* __restrict__ x,
                                                          const float* __restrict__ b1) {
    __shared__ char lA[128 * LDS1];   // 18432 B
    __shared__ char lB[128 * LDS1];   // 18432 B
    int t = threadIdx.x;
    if (blockIdx.x >= GEMM1_BLKS) {
        // ---- local branch (adapted to 512 threads) ----
        int b = blockIdx.x - GEMM1_BLKS;
        unsigned* hist = (unsigned*)lA;          // [256]
        unsigned* curs = hist + 256;             // [256]
        unsigned* wsum = curs + 256;             // [4]
        unsigned e0 = g_cstart[b], e1 = g_cstart[b + 1];
        if (t < 256) hist[t] = 0u;
        __syncthreads();
        for (unsigned e = e0 + t; e < e1; e += 512) atomicAdd(&hist[g_bin[e].y & 255], 1u);
        __syncthreads();
        unsigned v = (t < 256) ? hist[t] : 0u;
        int lane = t & 63, wv = t >> 6;
        unsigned sc = v;
#pragma unroll
        for (int off = 1; off < 64; off <<= 1) {
            unsigned n = __shfl_up(sc, off, 64);
            if (lane >= off) sc += n;
        }
        if (lane == 63 && wv < 4) wsum[wv] = sc;
        __syncthreads();
        unsigned woff = 0;
        for (int w = 0; w < 4; w++) if (w < wv) woff += wsum[w];
        unsigned excl = woff + sc - v;
        int node = b * 256 + t;
        if (t < 256 && node < NN) {
            g_rowstart[node] = e0 + excl;
            g_dinv[node] = v ? rsqrtf((float)v) : 0.0f;
        }
        if (b == 0 && t == 0) g_rowstart[NN] = NE;
        if (t < 256) curs[t] = excl;
        __syncthreads();
        for (unsigned e = e0 + t; e < e1; e += 512) {
            uint2 ed = g_bin[e];
            unsigned r = atomicAdd(&curs[ed.y & 255], 1u);
            g_csr_src[e0 + r] = (int)ed.x;
        }
        return;
    }
    // ---- gemm1 branch ----
    int group = blockIdx.x >> 4;              // 16 blocks per group: 8 mtiles x 2 ntiles
    int ntile = (blockIdx.x >> 3) & 1;
    int mtile = group * 8 + (blockIdx.x & 7);
    if (mtile >= NMT1) return;                // uniform per-block exit (tail group)
    int lane = t & 63, wv = t >> 6;           // wv 0..7
    int quad = lane >> 4, l16 = lane & 15;
    int mq = wv >> 1, nq = wv & 1;            // wave output: rows mq*32.., cols nq*64..

    // staging assignment: thread covers row r (0..127), 32-float chunk c (0..3)
    int r = t >> 2, c = t & 3;
    int gr = mtile * 128 + r; if (gr >= NN) gr = NN - 1;
    const float* xp = x + (size_t)gr * INC + c * 32;
    const signed char* wp = g_qw1 + (size_t)(ntile * 128 + r) * INC + c * 32;
    char* lap = lA + r * LDS1 + c * 32;
    char* lbp = lB + r * LDS1 + c * 32;

    float rsx = 1.0f / (__uint_as_float(g_amax_bits[0]) / 127.0f + 1e-12f);

    f32x4 ra[8];
    i32x4 rb[2];
#pragma unroll
    for (int k = 0; k < 8; k++) ra[k] = ((const f32x4*)xp)[k];
#pragma unroll
    for (int k = 0; k < 2; k++) rb[k] = ((const i32x4*)wp)[k];

    i32x4 acc[2][4] = {};
#pragma unroll 1
    for (int kit = 0; kit < 4; kit++) {
        // pack + LDS write (data loaded last iteration; vmcnt waits land here)
        i32x4 oa0 = pack16(ra[0], ra[1], ra[2], ra[3], rsx);
        i32x4 oa1 = pack16(ra[4], ra[5], ra[6], ra[7], rsx);
        *(i32x4*)(lap)      = oa0;
        *(i32x4*)(lap + 16) = oa1;
        *(i32x4*)(lbp)      = rb[0];
        *(i32x4*)(lbp + 16) = rb[1];
        __syncthreads();
        // fire-and-forget loads for next kit; drain happens at end-of-kit barrier
        if (kit < 3) {
#pragma unroll
            for (int k = 0; k < 8; k++) ra[k] = ((const f32x4*)(xp + (kit + 1) * 128))[k];
#pragma unroll
            for (int k = 0; k < 2; k++) rb[k] = ((const i32x4*)(wp + (kit + 1) * 128))[k];
        }
#pragma unroll
        for (int ks = 0; ks < 2; ks++) {
            int cs = ks * 64 + quad * 16;
            i32x4 a[2], b[4];
#pragma unroll
            for (int i = 0; i < 2; i++)
                a[i] = *(const i32x4*)(lA + (mq * 32 + i * 16 + l16) * LDS1 + cs);
#pragma unroll
            for (int j = 0; j < 4; j++)
                b[j] = *(const i32x4*)(lB + (nq * 64 + j * 16 + l16) * LDS1 + cs);
#pragma unroll
            for (int i = 0; i < 2; i++)
#pragma unroll
                for (int j = 0; j < 4; j++)
                    acc[i][j] = __builtin_amdgcn_mfma_i32_16x16x64_i8(a[i], b[j], acc[i][j], 0, 0, 0);
        }
        if (kit < 3) __syncthreads();   // reads done before next kit overwrites LDS
    }
    float s = (__uint_as_float(g_amax_bits[0]) / 127.0f + 1e-12f)
            * (__uint_as_float(g_amax_bits[1]) / 127.0f + 1e-12f);
    float lmax = 0.0f;
#pragma unroll
    for (int j = 0; j < 4; j++) {
        int col = ntile * 128 + nq * 64 + j * 16 + l16;
        float bias = b1[col];
#pragma unroll
        for (int i = 0; i < 2; i++) {
#pragma unroll
            for (int rr = 0; rr < 4; rr++) {
                int grow = mtile * 128 + mq * 32 + i * 16 + quad * 4 + rr;
                float v = fmaxf(s * (float)acc[i][j][rr] + bias, 0.0f);
                lmax = fmaxf(lmax, v);
                if (grow < NN) g_h[(size_t)grow * HID + col] = (_Float16)v;
            }
        }
    }
#pragma unroll
    for (int off = 32; off > 0; off >>= 1) lmax = fmaxf(lmax, __shfl_xor(lmax, off, 64));
    if (lane == 0) atomicMax(&g_amax_bits[3], __float_as_uint(lmax));
}

// ---------------- GEMM2: z = s * (fq(h) @ qw2^T) + b2 (int8 MFMA, fp16 h input) ----------------
__launch_bounds__(256)
__global__ void gemm2_kernel(const float* __restrict__ b2) {
    __shared__ char lB2[OCP * LDSB2];   // 13056 B
    __shared__ char lA2[128 * LDS1];    // 18432 B
    int t = threadIdx.x;
    int mtile = blockIdx.x;
    int lane = t & 63, wv = t >> 6;
    int quad = lane >> 4, l16 = lane & 15;

    // load qw2 int8 (48x256 = 12288 B) into padded LDS: 768 chunks of 16 B
#pragma unroll
    for (int p = 0; p < 3; p++) {
        int ci = p * 256 + t;          // 0..767
        int row = ci >> 4, ch = ci & 15;
        *(i32x4*)(lB2 + row * LDSB2 + ch * 16) =
            *(const i32x4*)(g_qw2 + row * 256 + ch * 16);
    }

    float scale_h = __uint_as_float(g_amax_bits[3]) / 127.0f + 1e-12f;
    float rs = 1.0f / scale_h;
    int srow = t >> 3, sch = t & 7;
    const _Float16* hbase[4];
#pragma unroll
    for (int p = 0; p < 4; p++) {
        int gr = mtile * 128 + p * 32 + srow; if (gr >= NN) gr = NN - 1;
        hbase[p] = g_h + (size_t)gr * HID + sch * 16;
    }

    i32x4 acc[2][3] = {};
#pragma unroll 1
    for (int kit = 0; kit < 2; kit++) {
        if (kit) __syncthreads();
#pragma unroll
        for (int p = 0; p < 4; p++) {
            int row = p * 32 + srow;
            const _Float16* hp = hbase[p] + kit * 128;
            f16x8 v0 = *(const f16x8*)(hp);
            f16x8 v1 = *(const f16x8*)(hp + 8);
            i32x4 o;
            o[0] = pack4((float)v0[0], (float)v0[1], (float)v0[2], (float)v0[3], rs);
            o[1] = pack4((float)v0[4], (float)v0[5], (float)v0[6], (float)v0[7], rs);
            o[2] = pack4((float)v1[0], (float)v1[1], (float)v1[2], (float)v1[3], rs);
            o[3] = pack4((float)v1[4], (float)v1[5], (float)v1[6], (float)v1[7], rs);
            *(i32x4*)(lA2 + row * LDS1 + sch * 16) = o;
        }
        __syncthreads();   // also orders the one-time lB2 fill before first use
#pragma unroll
        for (int ks = 0; ks < 2; ks++) {
            int cs = ks * 64 + quad * 16;
            i32x4 a[2], b[3];
#pragma unroll
            for (int i = 0; i < 2; i++)
                a[i] = *(const i32x4*)(lA2 + (wv * 32 + i * 16 + l16) * LDS1 + cs);
#pragma unroll
            for (int j = 0; j < 3; j++)
                b[j] = *(const i32x4*)(lB2 + (j * 16 + l16) * LDSB2 + kit * 128 + cs);
#pragma unroll
            for (int i = 0; i < 2; i++)
#pragma unroll
                for (int j = 0; j < 3; j++)
                    acc[i][j] = __builtin_amdgcn_mfma_i32_16x16x64_i8(a[i], b[j], acc[i][j], 0, 0, 0);
        }
    }
    float s = scale_h * (__uint_as_float(g_amax_bits[2]) / 127.0f + 1e-12f);
#pragma unroll
    for (int j = 0; j < 3; j++) {
        int col = j * 16 + l16;
        float bias = (col < OC) ? b2[col] : 0.0f;
#pragma unroll
        for (int i = 0; i < 2; i++) {
#pragma unroll
            for (int r = 0; r < 4; r++) {
                int grow = mtile * 128 + wv * 32 + i * 16 + quad * 4 + r;
                if (col < OC && grow < NN)
                    g_z[(size_t)grow * OC + col] = s * (float)acc[i][j][r] + bias;
            }
        }
    }
}

// ---------------- gather + fused log_softmax: one wave per node ----------------
__launch_bounds__(256)
__global__ void gather_kernel(float* __restrict__ out) {
    int node = (blockIdx.x * 256 + threadIdx.x) >> 6;
    int lane = threadIdx.x & 63;
    if (node >= NN) return;
    unsigned e0 = g_rowstart[node], e1 = g_rowstart[node + 1];
    float dinvd = g_dinv[node];
    bool ch = (lane < OC);
    float acc0 = 0.0f, acc1 = 0.0f;
    unsigned e = e0;
    for (; e + 8 <= e1; e += 8) {
        int s0 = g_csr_src[e],     s1 = g_csr_src[e + 1];
        int s2 = g_csr_src[e + 2], s3 = g_csr_src[e + 3];
        int s4 = g_csr_src[e + 4], s5 = g_csr_src[e + 5];
        int s6 = g_csr_src[e + 6], s7 = g_csr_src[e + 7];
        float c0 = g_dinv[s0], c1 = g_dinv[s1], c2 = g_dinv[s2], c3 = g_dinv[s3];
        float c4 = g_dinv[s4], c5 = g_dinv[s5], c6 = g_dinv[s6], c7 = g_dinv[s7];
        float z0 = ch ? g_z[(size_t)s0 * OC + lane] : 0.0f;
        float z1 = ch ? g_z[(size_t)s1 * OC + lane] : 0.0f;
        float z2 = ch ? g_z[(size_t)s2 * OC + lane] : 0.0f;
        float z3 = ch ? g_z[(size_t)s3 * OC + lane] : 0.0f;
        float z4 = ch ? g_z[(size_t)s4 * OC + lane] : 0.0f;
        float z5 = ch ? g_z[(size_t)s5 * OC + lane] : 0.0f;
        float z6 = ch ? g_z[(size_t)s6 * OC + lane] : 0.0f;
        float z7 = ch ? g_z[(size_t)s7 * OC + lane] : 0.0f;
        acc0 += (z0 * c0 + z1 * c1) + (z2 * c2 + z3 * c3);
        acc1 += (z4 * c4 + z5 * c5) + (z6 * c6 + z7 * c7);
    }
    for (; e + 4 <= e1; e += 4) {
        int s0 = g_csr_src[e],     s1 = g_csr_src[e + 1];
        int s2 = g_csr_src[e + 2], s3 = g_csr_src[e + 3];
        float c0 = g_dinv[s0], c1 = g_dinv[s1], c2 = g_dinv[s2], c3 = g_dinv[s3];
        float z0 = ch ? g_z[(size_t)s0 * OC + lane] : 0.0f;
        float z1 = ch ? g_z[(size_t)s1 * OC + lane] : 0.0f;
        float z2 = ch ? g_z[(size_t)s2 * OC + lane] : 0.0f;
        float z3 = ch ? g_z[(size_t)s3 * OC + lane] : 0.0f;
        acc0 += (z0 * c0 + z1 * c1) + (z2 * c2 + z3 * c3);
    }
    for (; e < e1; e++) {
        int s0 = g_csr_src[e];
        float z0 = ch ? g_z[(size_t)s0 * OC + lane] : 0.0f;
        acc1 += z0 * g_dinv[s0];
    }
    float acc = (acc0 + acc1) * dinvd;
    float m = ch ? acc : -1e30f;
#pragma unroll
    for (int off = 32; off > 0; off >>= 1) m = fmaxf(m, __shfl_xor(m, off, 64));
    float ex = ch ? __expf(acc - m) : 0.0f;
    float ssum = ex;
#pragma unroll
    for (int off = 32; off > 0; off >>= 1) ssum += __shfl_xor(ssum, off, 64);
    float lg = __logf(ssum);
    if (ch) out[(size_t)node * OC + lane] = acc - m - lg;
}

extern "C" void kernel_launch(void* const* d_in, const int* in_sizes, int n_in,
                              void* d_out, int out_size, void* d_ws, size_t ws_size,
                              hipStream_t stream) {
    const float* x  = (const float*)d_in[0];
    const int*   ei = (const int*)d_in[1];
    const float* w1 = (const float*)d_in[2];
    const float* b1 = (const float*)d_in[3];
    const float* w2 = (const float*)d_in[4];
    const float* b2 = (const float*)d_in[5];
    float* out = (float*)d_out;
    (void)d_ws; (void)ws_size; (void)in_sizes; (void)n_in; (void)out_size;

    init_kernel<<<64, 256, 0, stream>>>();
    absmax_chist_kernel<<<ABS_TOT + CHIST_BLKS, 256, 0, stream>>>(x, w1, w2, ei);
    cscan_kernel<<<1, 512, 0, stream>>>();
    quant_bin_kernel<<<QW_TOT + BIN_BLOCKS, 256, 0, stream>>>(w1, w2, ei);
    gemm1_local_kernel<<<GEMM1_BLKS + NBKT, 512, 0, stream>>>(x, b1);
    gemm2_kernel<<<(NN + 127) / 128, 256, 0, stream>>>(b2);
    gather_kernel<<<(NN + 3) / 4, 256, 0, stream>>>(out);
}

// Round 8
// 540.144 us; speedup vs baseline: 1.1252x; 1.1252x over previous
//
#include <hip/hip_runtime.h>
#include <hip/hip_bf16.h>
#include <hip/hip_fp16.h>
#include <stdint.h>
#include <stddef.h>

#define NN   100000   // nodes
#define NE   1600000  // edges
#define INC  512      // in channels
#define HID  256      // hidden
#define OC   40       // out channels
#define OCP  48       // padded out channels (3 x 16 col-tiles)

#define LDS1 144      // int8 tile row stride in bytes (128 + 16): conflict-free
#define LDSB2 272     // lB2 row stride bytes (256 + 16)

#define NBKT ((NN + 255) / 256)   // 391 coarse buckets of 256 nodes
#define NMT1 ((NN + 127) / 128)   // 782 gemm1 row tiles
#define GEMM1_BLKS (((NMT1 + 7) / 8) * 16)   // 1568

// L1 merged launch: absmax segments + chist
#define ABS_X_BLKS  2048
#define ABS_W1_BLKS 128
#define ABS_W2_BLKS 16
#define ABS_TOT     (ABS_X_BLKS + ABS_W1_BLKS + ABS_W2_BLKS)   // 2192
#define CHIST_BLKS  256
// L3 merged launch: quantw1 + quantw2 + bin (quantx fused into gemm1)
#define QW1_BLKS    128
#define QW2_BLKS    16
#define QW_TOT      (QW1_BLKS + QW2_BLKS)   // 144
#define BIN_BLOCKS  400
#define BIN_EPB     (NE / BIN_BLOCKS)   // 4000

typedef float  f32x4  __attribute__((ext_vector_type(4)));
typedef int    i32x4  __attribute__((ext_vector_type(4)));
typedef _Float16 f16x8 __attribute__((ext_vector_type(8)));

// ---- device-global scratch ----
__device__ unsigned g_amax_bits[4];          // 0:x 1:w1 2:w2 3:h
__device__ float    g_dinv[NN];
__device__ signed char g_qw1[HID * INC];         // int8
__device__ signed char g_qw2[OCP * HID];         // int8, rows 40..47 zero
__device__ _Float16 g_h[(size_t)NN * HID];   // relu(fc1) fp16
__device__ float    g_z[(size_t)NN * OC];    // fc2 output
// CSR-by-destination (two-level binned build)
__device__ unsigned g_chist[NBKT];
__device__ unsigned g_cstart[NBKT + 1];
__device__ unsigned g_ccur[NBKT];
__device__ uint2    g_bin[NE];
__device__ unsigned g_rowstart[NN + 1];
__device__ int      g_csr_src[NE];

__device__ __forceinline__ float quantf(float v, float rs) {
    return fminf(fmaxf(rintf(v * rs), -128.0f), 127.0f);
}
__device__ __forceinline__ int pack4(float a, float b, float c, float d, float rs) {
    int q0 = (int)quantf(a, rs), q1 = (int)quantf(b, rs);
    int q2 = (int)quantf(c, rs), q3 = (int)quantf(d, rs);
    return (q0 & 255) | ((q1 & 255) << 8) | ((q2 & 255) << 16) | ((q3 & 255) << 24);
}
__device__ __forceinline__ i32x4 pack16(f32x4 v0, f32x4 v1, f32x4 v2, f32x4 v3, float rs) {
    i32x4 o;
    o[0] = pack4(v0.x, v0.y, v0.z, v0.w, rs);
    o[1] = pack4(v1.x, v1.y, v1.z, v1.w, rs);
    o[2] = pack4(v2.x, v2.y, v2.z, v2.w, rs);
    o[3] = pack4(v3.x, v3.y, v3.z, v3.w, rs);
    return o;
}

// ---------------- init (tiny; must precede L1) ----------------
__global__ void init_kernel() {
    int idx = blockIdx.x * blockDim.x + threadIdx.x;
    int stride = gridDim.x * blockDim.x;
    for (int i = idx; i < NBKT; i += stride) g_chist[i] = 0u;
    for (int i = idx; i < (OCP * HID) / 4; i += stride) ((int*)g_qw2)[i] = 0;
    if (idx < 4) g_amax_bits[idx] = 0u;
}

// ---------------- L1: absmax(x|w1|w2) blocks [0,2192) + chist blocks [2192,2448) ----------------
__global__ void __launch_bounds__(256) absmax_chist_kernel(const float* __restrict__ x,
                                                           const float* __restrict__ w1,
                                                           const float* __restrict__ w2,
                                                           const int* __restrict__ ei) {
    __shared__ unsigned shist[NBKT];
    __shared__ float sm[4];
    int b = blockIdx.x;
    int t = threadIdx.x;
    if (b < ABS_TOT) {
        const float* src; int n4, slot, bbase, nb;
        if (b < ABS_X_BLKS) {
            src = x;  n4 = (NN * INC) / 4;  slot = 0; bbase = 0;                       nb = ABS_X_BLKS;
        } else if (b < ABS_X_BLKS + ABS_W1_BLKS) {
            src = w1; n4 = (HID * INC) / 4; slot = 1; bbase = ABS_X_BLKS;              nb = ABS_W1_BLKS;
        } else {
            src = w2; n4 = (OC * HID) / 4;  slot = 2; bbase = ABS_X_BLKS + ABS_W1_BLKS; nb = ABS_W2_BLKS;
        }
        int idx = (b - bbase) * 256 + t;
        int stride = nb * 256;
        const f32x4* s4 = (const f32x4*)src;
        float m = 0.0f;
        for (int i = idx; i < n4; i += stride) {
            f32x4 v = s4[i];
            m = fmaxf(m, fmaxf(fmaxf(fabsf(v.x), fabsf(v.y)),
                               fmaxf(fabsf(v.z), fabsf(v.w))));
        }
#pragma unroll
        for (int off = 32; off > 0; off >>= 1) m = fmaxf(m, __shfl_xor(m, off, 64));
        if ((t & 63) == 0) sm[t >> 6] = m;
        __syncthreads();
        if (t == 0) {
            float mm = fmaxf(fmaxf(sm[0], sm[1]), fmaxf(sm[2], sm[3]));
            atomicMax(&g_amax_bits[slot], __float_as_uint(mm));
        }
    } else {
        // chist: per-block LDS histogram of dst>>8, flush with global atomics
        const int* dst = ei + NE;
        for (int i = t; i < NBKT; i += 256) shist[i] = 0u;
        __syncthreads();
        int idx = (b - ABS_TOT) * 256 + t;
        int stride = CHIST_BLKS * 256;
        for (int e = idx; e < NE; e += stride) atomicAdd(&shist[dst[e] >> 8], 1u);
        __syncthreads();
        for (int i = t; i < NBKT; i += 256) {
            unsigned c = shist[i];
            if (c) atomicAdd(&g_chist[i], c);
        }
    }
}

// ---------------- coarse scan ----------------
__global__ void cscan_kernel() {
    int t = threadIdx.x;
    unsigned v = (t < NBKT) ? g_chist[t] : 0u;
    int lane = t & 63, wv = t >> 6;
    unsigned sc = v;
#pragma unroll
    for (int off = 1; off < 64; off <<= 1) {
        unsigned n = __shfl_up(sc, off, 64);
        if (lane >= off) sc += n;
    }
    __shared__ unsigned ws[8];
    if (lane == 63) ws[wv] = sc;
    __syncthreads();
    unsigned woff = 0;
    for (int w = 0; w < 8; w++) if (w < wv) woff += ws[w];
    unsigned excl = woff + sc - v;
    if (t < NBKT) { g_cstart[t] = excl; g_ccur[t] = excl; }
    if (t == 0) g_cstart[NBKT] = NE;
}

// ---------------- L3: quantw1 [0,128) + quantw2 [128,144) + bin [144,544) ----------------
__global__ void __launch_bounds__(256) quant_bin_kernel(const float* __restrict__ w1,
                                                        const float* __restrict__ w2,
                                                        const int* __restrict__ ei) {
    __shared__ unsigned hist[NBKT];
    __shared__ unsigned base[NBKT];
    int b = blockIdx.x;
    int t = threadIdx.x;
    if (b < QW_TOT) {
        const float* src; int* dst; int nint, slot, bbase, nb;
        if (b < QW1_BLKS) { src = w1; dst = (int*)g_qw1; nint = (HID * INC) / 4; slot = 1; bbase = 0;        nb = QW1_BLKS; }
        else              { src = w2; dst = (int*)g_qw2; nint = (OC * HID) / 4;  slot = 2; bbase = QW1_BLKS; nb = QW2_BLKS; }
        float rs = 1.0f / (__uint_as_float(g_amax_bits[slot]) / 127.0f + 1e-12f);
        int idx = (b - bbase) * 256 + t;
        int stride = nb * 256;
        for (int i = idx; i < nint; i += stride) {
            f32x4 v = *(const f32x4*)(src + (size_t)i * 4);
            dst[i] = pack4(v.x, v.y, v.z, v.w, rs);
        }
    } else {
        // bin: group edges by coarse bucket
        const int* srcp = ei;
        const int* dstp = ei + NE;
        int bb = b - QW_TOT;
        int e0 = bb * BIN_EPB, e1 = e0 + BIN_EPB;
        for (int i = t; i < NBKT; i += 256) hist[i] = 0u;
        __syncthreads();
        for (int e = e0 + t; e < e1; e += 256) atomicAdd(&hist[dstp[e] >> 8], 1u);
        __syncthreads();
        for (int i = t; i < NBKT; i += 256) {
            unsigned c = hist[i];
            base[i] = c ? atomicAdd(&g_ccur[i], c) : 0u;
            hist[i] = 0u;   // reuse as local cursor
        }
        __syncthreads();
        for (int e = e0 + t; e < e1; e += 256) {
            int d = dstp[e], s = srcp[e];
            int bk = d >> 8;
            unsigned r = atomicAdd(&hist[bk], 1u);
            g_bin[base[bk] + r] = make_uint2((unsigned)s, (unsigned)d);
        }
    }
}

// ---------------- L4 (256 threads): gemm1 [0,1568) + local [1568,1959) ----------------
// R6 structure (verified 120 us) + ONE fix: split-stage the A-side.  R6's
// loadpack16 packed immediately after the loads, exposing full load latency
// inside the prefetch.  Now: raw f32x4 loads fire-and-forget; the pack
// (bit-identical quantx math) runs at the NEXT kit's LDS-write, so the vmcnt
// drain is covered by barrier + 32-MFMA phase.  dbuf, 1 barrier/kit (write to
// buf[bs] at kit k+2 vs last read at kit k separated by barrier k+1).
__global__ void __launch_bounds__(256) gemm1_local_kernel(const float* __restrict__ x,
                                                          const float* __restrict__ b1) {
    __shared__ char lA[2][128 * LDS1];   // 2 x 18432 B
    __shared__ char lB[2][128 * LDS1];
    int t = threadIdx.x;
    if (blockIdx.x >= GEMM1_BLKS) {
        // ---- local branch ----
        int b = blockIdx.x - GEMM1_BLKS;
        unsigned* hist = (unsigned*)lA;          // [256]
        unsigned* curs = hist + 256;             // [256]
        unsigned* wsum = curs + 256;             // [4]
        unsigned e0 = g_cstart[b], e1 = g_cstart[b + 1];
        hist[t] = 0u;
        __syncthreads();
        for (unsigned e = e0 + t; e < e1; e += 256) atomicAdd(&hist[g_bin[e].y & 255], 1u);
        __syncthreads();
        unsigned v = hist[t];
        int lane = t & 63, wv = t >> 6;
        unsigned sc = v;
#pragma unroll
        for (int off = 1; off < 64; off <<= 1) {
            unsigned n = __shfl_up(sc, off, 64);
            if (lane >= off) sc += n;
        }
        if (lane == 63) wsum[wv] = sc;
        __syncthreads();
        unsigned woff = 0;
        for (int w = 0; w < 4; w++) if (w < wv) woff += wsum[w];
        unsigned excl = woff + sc - v;
        int node = b * 256 + t;
        if (node < NN) {
            g_rowstart[node] = e0 + excl;
            g_dinv[node] = v ? rsqrtf((float)v) : 0.0f;
        }
        if (b == 0 && t == 0) g_rowstart[NN] = NE;
        curs[t] = excl;
        __syncthreads();
        for (unsigned e = e0 + t; e < e1; e += 256) {
            uint2 ed = g_bin[e];
            unsigned r = atomicAdd(&curs[ed.y & 255], 1u);
            g_csr_src[e0 + r] = (int)ed.x;
        }
        return;
    }
    // ---- gemm1 branch ----
    int group = blockIdx.x >> 4;              // 16 blocks per group: 8 mtiles x 2 ntiles
    int ntile = (blockIdx.x >> 3) & 1;
    int mtile = group * 8 + (blockIdx.x & 7);
    if (mtile >= NMT1) return;                // uniform per-block exit (tail group)
    int lane = t & 63, wv = t >> 6;
    int quad = lane >> 4, l16 = lane & 15;
    int mq = wv >> 1, nq = wv & 1;

    int srow = t >> 3;     // 0..31
    int sch  = t & 7;      // 16-element chunk 0..7

    float rsx = 1.0f / (__uint_as_float(g_amax_bits[0]) / 127.0f + 1e-12f);

    const float* xb[4];
    const signed char* wb[4];
#pragma unroll
    for (int p = 0; p < 4; p++) {
        int gr = mtile * 128 + p * 32 + srow; if (gr >= NN) gr = NN - 1;
        xb[p] = x + (size_t)gr * INC + sch * 16;
        wb[p] = g_qw1 + (size_t)(ntile * 128 + p * 32 + srow) * INC + sch * 16;
    }

    f32x4 ra[4][4];          // raw fp32 staging (fire-and-forget loads)
    i32x4 bv[4];
#pragma unroll
    for (int p = 0; p < 4; p++) {
#pragma unroll
        for (int k = 0; k < 4; k++) ra[p][k] = ((const f32x4*)xb[p])[k];
        bv[p] = *(const i32x4*)(wb[p]);
    }

    i32x4 acc[4][4] = {};
#pragma unroll 1
    for (int kit = 0; kit < 4; kit++) {
        int bs = kit & 1;
        // pack (consumes loads issued last kit; drain covered by barrier+MFMA) + LDS write
#pragma unroll
        for (int p = 0; p < 4; p++) {
            int row = p * 32 + srow;
            i32x4 oa = pack16(ra[p][0], ra[p][1], ra[p][2], ra[p][3], rsx);
            *(i32x4*)(lA[bs] + row * LDS1 + sch * 16) = oa;
            *(i32x4*)(lB[bs] + row * LDS1 + sch * 16) = bv[p];
        }
        // fire-and-forget raw loads for kit+1
        if (kit + 1 < 4) {
#pragma unroll
            for (int p = 0; p < 4; p++) {
#pragma unroll
                for (int k = 0; k < 4; k++) ra[p][k] = ((const f32x4*)(xb[p] + (kit + 1) * 128))[k];
                bv[p] = *(const i32x4*)(wb[p] + (kit + 1) * 128);
            }
        }
        __syncthreads();
#pragma unroll
        for (int ks = 0; ks < 2; ks++) {
            int cs = ks * 64 + quad * 16;
            i32x4 a[4], b[4];
#pragma unroll
            for (int i = 0; i < 4; i++)
                a[i] = *(const i32x4*)(lA[bs] + (mq * 64 + i * 16 + l16) * LDS1 + cs);
#pragma unroll
            for (int j = 0; j < 4; j++)
                b[j] = *(const i32x4*)(lB[bs] + (nq * 64 + j * 16 + l16) * LDS1 + cs);
#pragma unroll
            for (int i = 0; i < 4; i++)
#pragma unroll
                for (int j = 0; j < 4; j++)
                    acc[i][j] = __builtin_amdgcn_mfma_i32_16x16x64_i8(a[i], b[j], acc[i][j], 0, 0, 0);
        }
    }
    float s = (__uint_as_float(g_amax_bits[0]) / 127.0f + 1e-12f)
            * (__uint_as_float(g_amax_bits[1]) / 127.0f + 1e-12f);
    float lmax = 0.0f;
#pragma unroll
    for (int j = 0; j < 4; j++) {
        int col = ntile * 128 + nq * 64 + j * 16 + l16;
        float bias = b1[col];
#pragma unroll
        for (int i = 0; i < 4; i++) {
#pragma unroll
            for (int r = 0; r < 4; r++) {
                int grow = mtile * 128 + mq * 64 + i * 16 + quad * 4 + r;
                float v = fmaxf(s * (float)acc[i][j][r] + bias, 0.0f);
                lmax = fmaxf(lmax, v);
                if (grow < NN) g_h[(size_t)grow * HID + col] = (_Float16)v;
            }
        }
    }
#pragma unroll
    for (int off = 32; off > 0; off >>= 1) lmax = fmaxf(lmax, __shfl_xor(lmax, off, 64));
    if (lane == 0) atomicMax(&g_amax_bits[3], __float_as_uint(lmax));
}

// ---------------- GEMM2: z = s * (fq(h) @ qw2^T) + b2 (int8 MFMA, fp16 h input) ----------------
__launch_bounds__(256)
__global__ void gemm2_kernel(const float* __restrict__ b2) {
    __shared__ char lB2[OCP * LDSB2];   // 13056 B
    __shared__ char lA2[128 * LDS1];    // 18432 B
    int t = threadIdx.x;
    int mtile = blockIdx.x;
    int lane = t & 63, wv = t >> 6;
    int quad = lane >> 4, l16 = lane & 15;

    // load qw2 int8 (48x256 = 12288 B) into padded LDS: 768 chunks of 16 B
#pragma unroll
    for (int p = 0; p < 3; p++) {
        int ci = p * 256 + t;          // 0..767
        int row = ci >> 4, ch = ci & 15;
        *(i32x4*)(lB2 + row * LDSB2 + ch * 16) =
            *(const i32x4*)(g_qw2 + row * 256 + ch * 16);
    }

    float scale_h = __uint_as_float(g_amax_bits[3]) / 127.0f + 1e-12f;
    float rs = 1.0f / scale_h;
    int srow = t >> 3, sch = t & 7;
    const _Float16* hbase[4];
#pragma unroll
    for (int p = 0; p < 4; p++) {
        int gr = mtile * 128 + p * 32 + srow; if (gr >= NN) gr = NN - 1;
        hbase[p] = g_h + (size_t)gr * HID + sch * 16;
    }

    i32x4 acc[2][3] = {};
#pragma unroll 1
    for (int kit = 0; kit < 2; kit++) {
        if (kit) __syncthreads();
#pragma unroll
        for (int p = 0; p < 4; p++) {
            int row = p * 32 + srow;
            const _Float16* hp = hbase[p] + kit * 128;
            f16x8 v0 = *(const f16x8*)(hp);
            f16x8 v1 = *(const f16x8*)(hp + 8);
            i32x4 o;
            o[0] = pack4((float)v0[0], (float)v0[1], (float)v0[2], (float)v0[3], rs);
            o[1] = pack4((float)v0[4], (float)v0[5], (float)v0[6], (float)v0[7], rs);
            o[2] = pack4((float)v1[0], (float)v1[1], (float)v1[2], (float)v1[3], rs);
            o[3] = pack4((float)v1[4], (float)v1[5], (float)v1[6], (float)v1[7], rs);
            *(i32x4*)(lA2 + row * LDS1 + sch * 16) = o;
        }
        __syncthreads();   // also orders the one-time lB2 fill before first use
#pragma unroll
        for (int ks = 0; ks < 2; ks++) {
            int cs = ks * 64 + quad * 16;
            i32x4 a[2], b[3];
#pragma unroll
            for (int i = 0; i < 2; i++)
                a[i] = *(const i32x4*)(lA2 + (wv * 32 + i * 16 + l16) * LDS1 + cs);
#pragma unroll
            for (int j = 0; j < 3; j++)
                b[j] = *(const i32x4*)(lB2 + (j * 16 + l16) * LDSB2 + kit * 128 + cs);
#pragma unroll
            for (int i = 0; i < 2; i++)
#pragma unroll
                for (int j = 0; j < 3; j++)
                    acc[i][j] = __builtin_amdgcn_mfma_i32_16x16x64_i8(a[i], b[j], acc[i][j], 0, 0, 0);
        }
    }
    float s = scale_h * (__uint_as_float(g_amax_bits[2]) / 127.0f + 1e-12f);
#pragma unroll
    for (int j = 0; j < 3; j++) {
        int col = j * 16 + l16;
        float bias = (col < OC) ? b2[col] : 0.0f;
#pragma unroll
        for (int i = 0; i < 2; i++) {
#pragma unroll
            for (int r = 0; r < 4; r++) {
                int grow = mtile * 128 + wv * 32 + i * 16 + quad * 4 + r;
                if (col < OC && grow < NN)
                    g_z[(size_t)grow * OC + col] = s * (float)acc[i][j][r] + bias;
            }
        }
    }
}

// ---------------- gather + fused log_softmax: one wave per node ----------------
__launch_bounds__(256)
__global__ void gather_kernel(float* __restrict__ out) {
    int node = (blockIdx.x * 256 + threadIdx.x) >> 6;
    int lane = threadIdx.x & 63;
    if (node >= NN) return;
    unsigned e0 = g_rowstart[node], e1 = g_rowstart[node + 1];
    float dinvd = g_dinv[node];
    bool ch = (lane < OC);
    float acc0 = 0.0f, acc1 = 0.0f;
    unsigned e = e0;
    for (; e + 8 <= e1; e += 8) {
        int s0 = g_csr_src[e],     s1 = g_csr_src[e + 1];
        int s2 = g_csr_src[e + 2], s3 = g_csr_src[e + 3];
        int s4 = g_csr_src[e + 4], s5 = g_csr_src[e + 5];
        int s6 = g_csr_src[e + 6], s7 = g_csr_src[e + 7];
        float c0 = g_dinv[s0], c1 = g_dinv[s1], c2 = g_dinv[s2], c3 = g_dinv[s3];
        float c4 = g_dinv[s4], c5 = g_dinv[s5], c6 = g_dinv[s6], c7 = g_dinv[s7];
        float z0 = ch ? g_z[(size_t)s0 * OC + lane] : 0.0f;
        float z1 = ch ? g_z[(size_t)s1 * OC + lane] : 0.0f;
        float z2 = ch ? g_z[(size_t)s2 * OC + lane] : 0.0f;
        float z3 = ch ? g_z[(size_t)s3 * OC + lane] : 0.0f;
        float z4 = ch ? g_z[(size_t)s4 * OC + lane] : 0.0f;
        float z5 = ch ? g_z[(size_t)s5 * OC + lane] : 0.0f;
        float z6 = ch ? g_z[(size_t)s6 * OC + lane] : 0.0f;
        float z7 = ch ? g_z[(size_t)s7 * OC + lane] : 0.0f;
        acc0 += (z0 * c0 + z1 * c1) + (z2 * c2 + z3 * c3);
        acc1 += (z4 * c4 + z5 * c5) + (z6 * c6 + z7 * c7);
    }
    for (; e + 4 <= e1; e += 4) {
        int s0 = g_csr_src[e],     s1 = g_csr_src[e + 1];
        int s2 = g_csr_src[e + 2], s3 = g_csr_src[e + 3];
        float c0 = g_dinv[s0], c1 = g_dinv[s1], c2 = g_dinv[s2], c3 = g_dinv[s3];
        float z0 = ch ? g_z[(size_t)s0 * OC + lane] : 0.0f;
        float z1 = ch ? g_z[(size_t)s1 * OC + lane] : 0.0f;
        float z2 = ch ? g_z[(size_t)s2 * OC + lane] : 0.0f;
        float z3 = ch ? g_z[(size_t)s3 * OC + lane] : 0.0f;
        acc0 += (z0 * c0 + z1 * c1) + (z2 * c2 + z3 * c3);
    }
    for (; e < e1; e++) {
        int s0 = g_csr_src[e];
        float z0 = ch ? g_z[(size_t)s0 * OC + lane] : 0.0f;
        acc1 += z0 * g_dinv[s0];
    }
    float acc = (acc0 + acc1) * dinvd;
    float m = ch ? acc : -1e30f;
#pragma unroll
    for (int off = 32; off > 0; off >>= 1) m = fmaxf(m, __shfl_xor(m, off, 64));
    float ex = ch ? __expf(acc - m) : 0.0f;
    float ssum = ex;
#pragma unroll
    for (int off = 32; off > 0; off >>= 1) ssum += __shfl_xor(ssum, off, 64);
    float lg = __logf(ssum);
    if (ch) out[(size_t)node * OC + lane] = acc - m - lg;
}

extern "C" void kernel_launch(void* const* d_in, const int* in_sizes, int n_in,
                              void* d_out, int out_size, void* d_ws, size_t ws_size,
                              hipStream_t stream) {
    const float* x  = (const float*)d_in[0];
    const int*   ei = (const int*)d_in[1];
    const float* w1 = (const float*)d_in[2];
    const float* b1 = (const float*)d_in[3];
    const float* w2 = (const float*)d_in[4];
    const float* b2 = (const float*)d_in[5];
    float* out = (float*)d_out;
    (void)d_ws; (void)ws_size; (void)in_sizes; (void)n_in; (void)out_size;

    init_kernel<<<64, 256, 0, stream>>>();
    absmax_chist_kernel<<<ABS_TOT + CHIST_BLKS, 256, 0, stream>>>(x, w1, w2, ei);
    cscan_kernel<<<1, 512, 0, stream>>>();
    quant_bin_kernel<<<QW_TOT + BIN_BLOCKS, 256, 0, stream>>>(w1, w2, ei);
    gemm1_local_kernel<<<GEMM1_BLKS + NBKT, 256, 0, stream>>>(x, b1);
    gemm2_kernel<<<(NN + 127) / 128, 256, 0, stream>>>(b2);
    gather_kernel<<<(NN + 3) / 4, 256, 0, stream>>>(out);
}